// Round 12
// baseline (344.205 us; speedup 1.0000x reference)
//
#include <hip/hip_runtime.h>

using u16 = unsigned short;
using u32 = unsigned int;

typedef __attribute__((ext_vector_type(8))) __bf16 bf16x8;
typedef __attribute__((ext_vector_type(4))) float f32x4;
typedef __attribute__((ext_vector_type(16))) float f32x16;

#define DEVI __device__ __forceinline__

DEVI float bf2f(u16 u) {
  union { u32 i; float f; } v; v.i = ((u32)u) << 16; return v.f;
}
DEVI u16 f2bf(float f) {
  union { float f; u32 u; } v; v.f = f;
  u32 u = v.u;
  u32 r = (u + 0x7fffu + ((u >> 16) & 1u)) >> 16;
  return (u16)r;
}
// pack two f32 -> one u32 of 2x bf16 (compiler emits v_cvt_pk_bf16_f32)
DEVI u32 pkbf(float a, float b) {
  union { __bf16 h[2]; u32 u; } t;
  t.h[0] = (__bf16)a; t.h[1] = (__bf16)b;
  return t.u;
}

// async global->LDS, 16B per lane. LDS dest = wave-uniform base + lane*16.
DEVI void gload16(const u16* g, u16* l) {
  __builtin_amdgcn_global_load_lds(
      (const __attribute__((address_space(1))) void*)g,
      (__attribute__((address_space(3))) void*)l, 16, 0, 0);
}

// P-row (16 f32) -> PV A-fragment via cvt_pk + permlane32_swap (verified R3-R10)
DEVI bf16x8 packP(const float* pp) {
  u32 a01 = pkbf(pp[0], pp[1]);
  u32 a23 = pkbf(pp[2], pp[3]);
  u32 a45 = pkbf(pp[4], pp[5]);
  u32 a67 = pkbf(pp[6], pp[7]);
  asm volatile("v_permlane32_swap_b32 %0, %1" : "+v"(a01), "+v"(a45));
  asm volatile("v_permlane32_swap_b32 %0, %1" : "+v"(a23), "+v"(a67));
  union { u32 w[4]; bf16x8 v; } pf;
  pf.w[0] = a01; pf.w[1] = a23; pf.w[2] = a45; pf.w[3] = a67;
  return pf.v;
}

// tree-sum of 16 floats (depth 4)
DEVI float sum16(const float* p) {
  float a0 = p[0] + p[1],  a1 = p[2] + p[3];
  float a2 = p[4] + p[5],  a3 = p[6] + p[7];
  float a4 = p[8] + p[9],  a5 = p[10] + p[11];
  float a6 = p[12] + p[13], a7 = p[14] + p[15];
  float b0 = a0 + a1, b1 = a2 + a3, b2 = a4 + a5, b3 = a6 + a7;
  return (b0 + b1) + (b2 + b3);
}

// ------- 64x64 transpose+convert body: in[R][Cc] f32 -> out[Cc][R] bf16 -------
DEVI void tcvt64_body(const float* in, u16* out, int R, int Cc, int c0, int r0, int t,
                      u16 (*tile)[72]) {
  {
    int row = t >> 2, part = t & 3;
    const float* src = in + (size_t)(r0 + row) * Cc + c0 + part * 16;
    float4 f0 = ((const float4*)src)[0];
    float4 f1 = ((const float4*)src)[1];
    float4 f2 = ((const float4*)src)[2];
    float4 f3 = ((const float4*)src)[3];
    u16 v[16] = {f2bf(f0.x), f2bf(f0.y), f2bf(f0.z), f2bf(f0.w),
                 f2bf(f1.x), f2bf(f1.y), f2bf(f1.z), f2bf(f1.w),
                 f2bf(f2.x), f2bf(f2.y), f2bf(f2.z), f2bf(f2.w),
                 f2bf(f3.x), f2bf(f3.y), f2bf(f3.z), f2bf(f3.w)};
    *(uint4*)&tile[row][part * 16]     = ((const uint4*)v)[0];
    *(uint4*)&tile[row][part * 16 + 8] = ((const uint4*)v)[1];
  }
  __syncthreads();
  {
    int c = t & 63, rq = t >> 6;
    u16 v[16];
#pragma unroll
    for (int i = 0; i < 16; i++) v[i] = tile[rq * 16 + i][c];
    u16* dst = out + (size_t)(c0 + c) * R + r0 + rq * 16;
    ((uint4*)dst)[0] = ((const uint4*)v)[0];
    ((uint4*)dst)[1] = ((const uint4*)v)[1];
  }
}

// ---------------- cvt x: fp32 -> bf16, 8 elems/thread ----------------
__global__ __launch_bounds__(256) void cvt_bf16_f32(const float* __restrict__ in,
                                                    u16* __restrict__ out, int n8) {
  int i = blockIdx.x * 256 + threadIdx.x;
  if (i >= n8) return;
  const float4* fin = (const float4*)in;
  float4 a = fin[i * 2], b = fin[i * 2 + 1];
  u16 o[8] = {f2bf(a.x), f2bf(a.y), f2bf(a.z), f2bf(a.w),
              f2bf(b.x), f2bf(b.y), f2bf(b.z), f2bf(b.w)};
  ((uint4*)out)[i] = *(const uint4*)o;
}

__global__ __launch_bounds__(256) void transpose_cvt64(const float* __restrict__ in,
                                                       u16* __restrict__ out,
                                                       int R, int Cc) {
  __shared__ u16 tile[64][72];
  tcvt64_body(in, out, R, Cc, blockIdx.x * 64, blockIdx.y * 64, threadIdx.x, tile);
}

// ---- fused Wq/Wk/Wv transpose (fallback path) ----
__global__ __launch_bounds__(256) void transpose_wqkv(const float* __restrict__ Wq,
                                                      const float* __restrict__ Wk,
                                                      const float* __restrict__ Wv,
                                                      u16* __restrict__ out) {
  __shared__ u16 tile[64][72];
  int bx = blockIdx.x;
  const float* in;
  u16* dst;
  int Cc, c0;
  if (bx < 32)      { in = Wq; dst = out;                        Cc = 2048; c0 = bx * 64; }
  else if (bx < 40) { in = Wk; dst = out + (size_t)2048 * 2048;  Cc = 512;  c0 = (bx - 32) * 64; }
  else              { in = Wv; dst = out + (size_t)2560 * 2048;  Cc = 512;  c0 = (bx - 40) * 64; }
  tcvt64_body(in, dst, 2048, Cc, c0, blockIdx.y * 64, threadIdx.x, tile);
}

// ---- ALL preprocessing in ONE launch (grid-sliced), R10-verified ----
__global__ __launch_bounds__(256) void prep_all(const float* __restrict__ x,
                                                const float* __restrict__ Wq,
                                                const float* __restrict__ Wk,
                                                const float* __restrict__ Wv,
                                                const float* __restrict__ Wo,
                                                u16* __restrict__ xb,
                                                u16* __restrict__ WqkvT,
                                                u16* __restrict__ WoT) {
  __shared__ u16 tile[64][72];
  int id = blockIdx.x;
  if (id < 4096) {
    int i = id * 256 + threadIdx.x;
    const float4* fin = (const float4*)x;
    float4 a = fin[i * 2], b = fin[i * 2 + 1];
    u16 o[8] = {f2bf(a.x), f2bf(a.y), f2bf(a.z), f2bf(a.w),
                f2bf(b.x), f2bf(b.y), f2bf(b.z), f2bf(b.w)};
    ((uint4*)xb)[i] = *(const uint4*)o;
    return;
  }
  id -= 4096;
  if (id < 1536) {
    int bx = id % 48, by = id / 48;
    const float* in;
    u16* dst;
    int Cc, c0;
    if (bx < 32)      { in = Wq; dst = WqkvT;                        Cc = 2048; c0 = bx * 64; }
    else if (bx < 40) { in = Wk; dst = WqkvT + (size_t)2048 * 2048;  Cc = 512;  c0 = (bx - 32) * 64; }
    else              { in = Wv; dst = WqkvT + (size_t)2560 * 2048;  Cc = 512;  c0 = (bx - 40) * 64; }
    tcvt64_body(in, dst, 2048, Cc, c0, by * 64, threadIdx.x, tile);
    return;
  }
  id -= 1536;
  int bx = id & 31, by = id >> 5;
  tcvt64_body(Wo, WoT, 2048, 2048, bx * 64, by * 64, threadIdx.x, tile);
}

// ---- 64x64 vectorized bf16 transpose with input row-stride (V slice) ----
__global__ __launch_bounds__(256) void transpose_sl64(const u16* __restrict__ in, int ldin,
                                                      u16* __restrict__ out,
                                                      int R, int Cc) {
  __shared__ u16 tile[64][72];
  int c0 = blockIdx.x * 64, r0 = blockIdx.y * 64;
  int t = threadIdx.x;
  {
    int row = t >> 2, part = t & 3;
    const u16* src = in + (size_t)(r0 + row) * ldin + c0 + part * 16;
    uint4 a = ((const uint4*)src)[0];
    uint4 b = ((const uint4*)src)[1];
    *(uint4*)&tile[row][part * 16]     = a;
    *(uint4*)&tile[row][part * 16 + 8] = b;
  }
  __syncthreads();
  {
    int c = t & 63, rq = t >> 6;
    u16 v[16];
#pragma unroll
    for (int i = 0; i < 16; i++) v[i] = tile[rq * 16 + i][c];
    u16* dst = out + (size_t)(c0 + c) * R + r0 + rq * 16;
    ((uint4*)dst)[0] = ((const uint4*)v)[0];
    ((uint4*)dst)[1] = ((const uint4*)v)[1];
  }
}

// ---- GEMM: C[M,N] = A[M,K] * Bt[N,K]^T, 128x128 tile, BK=32, 2-phase dbuf ----
// R8-verified: T1 XCD swizzle (bijective) + ROPE epilogue. Frozen.
DEVI void cstore(u16* C, size_t idx, float v)   { C[idx] = f2bf(v); }
DEVI void cstore(float* C, size_t idx, float v) { C[idx] = v; }

template <typename TO, bool ROPE>
__global__ __launch_bounds__(256) void gemm128(const u16* __restrict__ A,
                                               const u16* __restrict__ Bt,
                                               TO* __restrict__ C,
                                               int M, int N, int K) {
  __shared__ u16 As[2 * 128 * 32];
  __shared__ u16 Bs[2 * 128 * 32];
  int tid = threadIdx.x, wid = tid >> 6, lane = tid & 63;
  int quad = lane >> 4, l15 = lane & 15;

  // T1 XCD swizzle: contiguous grid chunk per XCD (requires nwg % 8 == 0)
  int nwg = gridDim.x * gridDim.y;
  int bid = blockIdx.y * gridDim.x + blockIdx.x;
  int swz = (bid & 7) * (nwg >> 3) + (bid >> 3);
  int bx = swz % gridDim.x, by = swz / gridDim.x;
  int m0 = by * 128, n0 = bx * 128;
  int wm = (wid >> 1) * 64, wn = (wid & 1) * 64;

  int r0s = wid * 16 + (lane >> 2);
  int r1s = 64 + wid * 16 + (lane >> 2);
  int cblk = lane & 3;
  int cs0 = (cblk ^ ((r0s >> 1) & 3)) * 8;
  int cs1 = (cblk ^ ((r1s >> 1) & 3)) * 8;
  u16* lA0 = As + wid * 512 + lane * 8;
  u16* lA1 = As + (4 + wid) * 512 + lane * 8;
  u16* lB0 = Bs + wid * 512 + lane * 8;
  u16* lB1 = Bs + (4 + wid) * 512 + lane * 8;
  const u16* gA0 = A + (size_t)(m0 + r0s) * K + cs0;
  const u16* gA1 = A + (size_t)(m0 + r1s) * K + cs1;
  const u16* gB0 = Bt + (size_t)(n0 + r0s) * K + cs0;
  const u16* gB1 = Bt + (size_t)(n0 + r1s) * K + cs1;

  f32x4 acc[4][4];
  for (int i = 0; i < 4; i++)
    for (int j = 0; j < 4; j++) acc[i][j] = f32x4{0.f, 0.f, 0.f, 0.f};

  // prologue: stage K-step 0 into buf 0
  gload16(gA0, lA0);
  gload16(gA1, lA1);
  gload16(gB0, lB0);
  gload16(gB1, lB1);
  __builtin_amdgcn_s_waitcnt(0x0F70);  // vmcnt(0)
  __syncthreads();

  int cur = 0;
  for (int k0 = 0; k0 < K; k0 += 32) {
    int nb = cur ^ 1;
    if (k0 + 32 < K) {                 // prefetch next K-step into other buf
      gload16(gA0 + k0 + 32, lA0 + nb * 4096);
      gload16(gA1 + k0 + 32, lA1 + nb * 4096);
      gload16(gB0 + k0 + 32, lB0 + nb * 4096);
      gload16(gB1 + k0 + 32, lB1 + nb * 4096);
    }
    const u16* Ab = As + cur * 4096;
    const u16* Bb = Bs + cur * 4096;
    bf16x8 af[4], bf_[4];
    for (int mi = 0; mi < 4; mi++) {
      int row = wm + mi * 16 + l15;
      af[mi] = *(const bf16x8*)(Ab + row * 32 + ((quad ^ ((row >> 1) & 3)) * 8));
    }
    for (int ni = 0; ni < 4; ni++) {
      int row = wn + ni * 16 + l15;
      bf_[ni] = *(const bf16x8*)(Bb + row * 32 + ((quad ^ ((row >> 1) & 3)) * 8));
    }
    for (int mi = 0; mi < 4; mi++)
      for (int ni = 0; ni < 4; ni++)
        acc[mi][ni] = __builtin_amdgcn_mfma_f32_16x16x32_bf16(af[mi], bf_[ni], acc[mi][ni], 0, 0, 0);
    __builtin_amdgcn_s_waitcnt(0x0F70);  // vmcnt(0): prefetch landed
    __syncthreads();                     // one barrier per K-step
    cur = nb;
  }

  if (ROPE) {
    // rotate (d, d+32) pairs for Q (cols<2048, scale folded) and K (2048..2560)
#pragma unroll
    for (int ni = 0; ni < 2; ni++) {
      int nc = n0 + wn + ni * 16;            // block-uniform
      if (nc < 2560) {
        float scale = (nc < 2048) ? 0.18033688f : 1.0f;  // (1/8)*log2(e) for Q
        float inv = exp2f(-(float)(ni * 16 + l15) * 0.59161152f);  // theta^-(d/32)
#pragma unroll
        for (int mi = 0; mi < 4; mi++)
#pragma unroll
          for (int r = 0; r < 4; r++) {
            int t = (m0 + wm + mi * 16 + quad * 4 + r) & 2047;
            float sn, cs;
            __sincosf((float)t * inv, &sn, &cs);
            float xl = acc[mi][ni][r], xh = acc[mi][ni + 2][r];
            acc[mi][ni][r]     = (xl * cs - xh * sn) * scale;
            acc[mi][ni + 2][r] = (xh * cs + xl * sn) * scale;
          }
      }
    }
  }

  for (int mi = 0; mi < 4; mi++)
    for (int ni = 0; ni < 4; ni++)
      for (int r = 0; r < 4; r++) {
        int row = m0 + wm + mi * 16 + quad * 4 + r;
        int col = n0 + wn + ni * 16 + l15;
        cstore(C, (size_t)row * N + col, acc[mi][ni][r]);
      }
}

// ---------------- Flash attention v9: QK-ahead subtile pipeline ----------------
// R10 counters (stable 4 rounds): MfmaUtil 15.5, VALUBusy 54, idle ~30 at the
// grid-capped 2 waves/SIMD -> the wave stalls on its own QK chain before each
// softmax. v9 reorders each 64-key tile: QK(sub0); QK(sub1); SM+PV(sub0);
// SM+PV(sub1). Sub1's 16 independent QK MFMAs now execute UNDER sub0's softmax
// VALU, and softmax(sub1) finds its S ready (no second stall). setprio removed
// (R10 null). Causal flags per-sub, wave-uniform; barriers unconditional.
// (R11 bench was an infra failure; source re-audited, resubmitted unchanged.)
__global__ __launch_bounds__(256) void attn64(const u16* __restrict__ QKV,
                                              const u16* __restrict__ Vt,
                                              u16* __restrict__ Y) {
  __shared__ u16 Ks[2 * 64 * 64];   // 2 bufs, [key][d], granule-swizzled
  __shared__ u16 Vst[2 * 64 * 64];  // 2 bufs, [d][key], granule-swizzled

  int tid = threadIdx.x, wid = tid >> 6, lane = tid & 63;
  int l31 = lane & 31, hi = lane >> 5;
  int bh = blockIdx.y, b = bh >> 5, h = bh & 31, kvh = h >> 2;
  int p = blockIdx.x;                       // 0..7
  int jA = p, jB = 15 - p;

  // K staging (global_load_lds, linear dest + inverse-swizzled src)
  int kr  = wid * 8 + (lane >> 3);
  int kgn = lane & 7;
  const u16* gK0 = QKV + (size_t)(b * 2048 + kr) * 3072 + 2048 + kvh * 64
                 + ((kgn ^ (kr & 7)) * 8);
  u16* lK0 = Ks + wid * 512 + lane * 8;     // +buf*4096; +2048 for rows+32

  // V staging (reg-staged, swizzled ds_write)
  int vr = tid >> 3, vg = tid & 7;
  const u16* gV0 = Vt + (size_t)(kvh * 64 + vr) * 4096 + b * 2048 + vg * 8;
  u16* lV0 = Vst + vr * 64 + ((vg ^ (vr & 7)) * 8);  // +buf*4096; +2048 for d+32

  int q0wA = jA * 128 + wid * 32, qgA = q0wA + l31;
  int q0wB = jB * 128 + wid * 32, qgB = q0wB + l31;

  // Q fragments (RoPE'd + scale-folded by the QKV gemm epilogue)
  bf16x8 qfA[4], qfB[4];
  {
    const u16* qpA = QKV + (size_t)(b * 2048 + qgA) * 3072 + h * 64 + hi * 8;
    const u16* qpB = QKV + (size_t)(b * 2048 + qgB) * 3072 + h * 64 + hi * 8;
#pragma unroll
    for (int dh = 0; dh < 4; dh++) {
      qfA[dh] = *(const bf16x8*)(qpA + dh * 16);
      qfB[dh] = *(const bf16x8*)(qpB + dh * 16);
    }
  }

  f32x16 o0A, o1A, o0B, o1B;
#pragma unroll
  for (int i = 0; i < 16; i++) { o0A[i] = 0.f; o1A[i] = 0.f; o0B[i] = 0.f; o1B[i] = 0.f; }
  float zsumA = 0.f, zsumB = 0.f;

  int nkt = 2 * (jB + 1);                   // covers both strips (jB >= jA)

  // prologue: stage tile 0 into buf 0
  {
    uint4 va = *(const uint4*)(gV0);
    uint4 vb = *(const uint4*)(gV0 + 32 * 4096);
    gload16(gK0, lK0);
    gload16(gK0 + 32 * 3072, lK0 + 2048);
    __builtin_amdgcn_s_waitcnt(0x0F70);     // vmcnt(0)
    *(uint4*)(lV0)        = va;
    *(uint4*)(lV0 + 2048) = vb;
  }
  __syncthreads();

// QK phase for sub SUB into SA (if dual) and SB
#define QKP(SUB, SA, SB, DUAL)                                                   \
  do {                                                                           \
    if (DUAL) {                                                                  \
      _Pragma("unroll") for (int i = 0; i < 16; i++) { SA[i] = 0.f; SB[i] = 0.f; } \
      _Pragma("unroll") for (int dh = 0; dh < 4; dh++) {                         \
        int g = (dh * 2 + hi) ^ (l31 & 7);                                       \
        bf16x8 kf = *(const bf16x8*)(Kb + ((SUB) * 32 + l31) * 64 + g * 8);      \
        SA = __builtin_amdgcn_mfma_f32_32x32x16_bf16(kf, qfA[dh], SA, 0, 0, 0);  \
        SB = __builtin_amdgcn_mfma_f32_32x32x16_bf16(kf, qfB[dh], SB, 0, 0, 0);  \
      }                                                                          \
    } else {                                                                     \
      _Pragma("unroll") for (int i = 0; i < 16; i++) SB[i] = 0.f;                \
      _Pragma("unroll") for (int dh = 0; dh < 4; dh++) {                         \
        int g = (dh * 2 + hi) ^ (l31 & 7);                                       \
        bf16x8 kf = *(const bf16x8*)(Kb + ((SUB) * 32 + l31) * 64 + g * 8);      \
        SB = __builtin_amdgcn_mfma_f32_32x32x16_bf16(kf, qfB[dh], SB, 0, 0, 0);  \
      }                                                                          \
    }                                                                            \
  } while (0)

// softmax + PV phase for sub SUB (kb = KB) using SA/SB
#define SMPV(SUB, KB, SA, SB, DUAL)                                              \
  do {                                                                           \
    if (DUAL) {                                                                  \
      float pbA[16], pbB[16];                                                    \
      if ((KB) < q0wA) {                                                         \
        _Pragma("unroll") for (int r = 0; r < 16; r++) pbA[r] = exp2f(SA[r]);    \
      } else {                                                                   \
        _Pragma("unroll") for (int r = 0; r < 16; r++) {                         \
          int key = (KB) + (r & 3) + 8 * (r >> 2) + 4 * hi;                      \
          pbA[r] = (key <= qgA) ? exp2f(SA[r]) : 0.f;                            \
        }                                                                        \
      }                                                                          \
      _Pragma("unroll") for (int r = 0; r < 16; r++) pbB[r] = exp2f(SB[r]);      \
      zsumA += sum16(pbA);                                                       \
      zsumB += sum16(pbB);                                                       \
      bf16x8 pfA0 = packP(pbA), pfA1 = packP(pbA + 8);                           \
      bf16x8 pfB0 = packP(pbB), pfB1 = packP(pbB + 8);                           \
      _Pragma("unroll") for (int kk = 0; kk < 2; kk++) {                         \
        int kgr = (SUB) * 4 + kk * 2 + hi;                                       \
        const u16* vp = Vb + l31 * 64 + ((kgr ^ (l31 & 7)) * 8);                 \
        bf16x8 v0 = *(const bf16x8*)(vp);                                        \
        bf16x8 v1 = *(const bf16x8*)(vp + 2048);                                 \
        bf16x8 pA = kk ? pfA1 : pfA0;                                            \
        bf16x8 pB = kk ? pfB1 : pfB0;                                            \
        o0A = __builtin_amdgcn_mfma_f32_32x32x16_bf16(pA, v0, o0A, 0, 0, 0);     \
        o1A = __builtin_amdgcn_mfma_f32_32x32x16_bf16(pA, v1, o1A, 0, 0, 0);     \
        o0B = __builtin_amdgcn_mfma_f32_32x32x16_bf16(pB, v0, o0B, 0, 0, 0);     \
        o1B = __builtin_amdgcn_mfma_f32_32x32x16_bf16(pB, v1, o1B, 0, 0, 0);     \
      }                                                                          \
    } else {                                                                     \
      float pb[16];                                                              \
      if ((KB) < q0wB) {                                                         \
        _Pragma("unroll") for (int r = 0; r < 16; r++) pb[r] = exp2f(SB[r]);     \
      } else {                                                                   \
        _Pragma("unroll") for (int r = 0; r < 16; r++) {                         \
          int key = (KB) + (r & 3) + 8 * (r >> 2) + 4 * hi;                      \
          pb[r] = (key <= qgB) ? exp2f(SB[r]) : 0.f;                             \
        }                                                                        \
      }                                                                          \
      zsumB += sum16(pb);                                                        \
      bf16x8 pf0 = packP(pb), pf1 = packP(pb + 8);                               \
      _Pragma("unroll") for (int kk = 0; kk < 2; kk++) {                         \
        int kgr = (SUB) * 4 + kk * 2 + hi;                                       \
        const u16* vp = Vb + l31 * 64 + ((kgr ^ (l31 & 7)) * 8);                 \
        bf16x8 v0 = *(const bf16x8*)(vp);                                        \
        bf16x8 v1 = *(const bf16x8*)(vp + 2048);                                 \
        bf16x8 pB = kk ? pf1 : pf0;                                              \
        o0B = __builtin_amdgcn_mfma_f32_32x32x16_bf16(pB, v0, o0B, 0, 0, 0);     \
        o1B = __builtin_amdgcn_mfma_f32_32x32x16_bf16(pB, v1, o1B, 0, 0, 0);     \
      }                                                                          \
    }                                                                            \
  } while (0)

  int cur = 0;
  for (int kt = 0; kt < nkt; kt++) {
    int kbase = kt * 64;
    int nxt = cur ^ 1;
    bool more = (kt + 1 < nkt);
    uint4 va, vb;
    if (more) {                             // issue next tile's loads early
      size_t ko = (size_t)(kbase + 64);
      va = *(const uint4*)(gV0 + ko);
      vb = *(const uint4*)(gV0 + 32 * 4096 + ko);
      gload16(gK0 + ko * 3072, lK0 + nxt * 4096);
      gload16(gK0 + ko * 3072 + 32 * 3072, lK0 + nxt * 4096 + 2048);
    }

    const u16* Kb = Ks + cur * 4096;
    const u16* Vb = Vst + cur * 4096;
    int kb0 = kbase, kb1 = kbase + 32;
    bool run0 = (kb0 <= q0wB), run1 = (kb1 <= q0wB);
    bool dual0 = (kb0 <= q0wA), dual1 = (kb1 <= q0wA);

    f32x16 sA0, sB0, sA1, sB1;
    // QK-ahead: issue both subs' QK chains before any softmax consumes them
    if (run0) QKP(0, sA0, sB0, dual0);
    if (run1) QKP(1, sA1, sB1, dual1);
    if (run0) SMPV(0, kb0, sA0, sB0, dual0);
    if (run1) SMPV(1, kb1, sA1, sB1, dual1);

    if (more) {
      __builtin_amdgcn_s_waitcnt(0x0F70);   // vmcnt(0): K in LDS, V in regs
      *(uint4*)(lV0 + nxt * 4096)        = va;
      *(uint4*)(lV0 + nxt * 4096 + 2048) = vb;
    }
    __syncthreads();                        // one barrier per shared 64-key tile
    cur = nxt;
  }
#undef QKP
#undef SMPV

  // epilogue, strip A
  {
    float zf = zsumA + __shfl_xor(zsumA, 32);
#pragma unroll
    for (int r = 0; r < 16; r++) {
      int qr = (r & 3) + 8 * (r >> 2) + 4 * hi;
      float zr = __shfl(zf, qr, 64);
      float inv = 1.f / zr;
      size_t row = (size_t)(b * 2048 + q0wA + qr);
      Y[row * 2048 + h * 64 + l31]      = f2bf(o0A[r] * inv);
      Y[row * 2048 + h * 64 + 32 + l31] = f2bf(o1A[r] * inv);
    }
  }
  // epilogue, strip B
  {
    float zf = zsumB + __shfl_xor(zsumB, 32);
#pragma unroll
    for (int r = 0; r < 16; r++) {
      int qr = (r & 3) + 8 * (r >> 2) + 4 * hi;
      float zr = __shfl(zf, qr, 64);
      float inv = 1.f / zr;
      size_t row = (size_t)(b * 2048 + q0wB + qr);
      Y[row * 2048 + h * 64 + l31]      = f2bf(o0B[r] * inv);
      Y[row * 2048 + h * 64 + 32 + l31] = f2bf(o1B[r] * inv);
    }
  }
}

extern "C" void kernel_launch(void* const* d_in, const int* in_sizes, int n_in,
                              void* d_out, int out_size, void* d_ws, size_t ws_size,
                              hipStream_t stream) {
  const float* x  = (const float*)d_in[0];  // [4096][2048] fp32
  const float* Wq = (const float*)d_in[1];  // [2048][2048]
  const float* Wk = (const float*)d_in[2];  // [2048][512]
  const float* Wv = (const float*)d_in[3];  // [2048][512]
  const float* Wo = (const float*)d_in[4];  // [2048][2048]
  float* outp = (float*)d_out;              // fp32 out

  // workspace (u16 units)
  u16* xb    = (u16*)d_ws;             // [4096][2048]   8388608
  u16* WqkvT = xb + 8388608;           // [3072][2048]   6291456
  u16* QKV   = WqkvT + 6291456;        // [4096][3072]  12582912
  u16* Vt    = QKV + 12582912;         // [512][4096]    2097152
  u16* Yb    = xb;                     // reuse (xb dead after QKV gemm)

  // big-ws path: WoT gets its own slab -> all preprocessing in one launch
  bool bigws = ws_size >= (size_t)(33554432) * 2;  // 64 MB
  u16* WoT = bigws ? (Vt + 2097152) : WqkvT;       // fallback: alias WqkvT

  if (bigws) {
    prep_all<<<6656, 256, 0, stream>>>(x, Wq, Wk, Wv, Wo, xb, WqkvT, WoT);
  } else {
    cvt_bf16_f32<<<4096, 256, 0, stream>>>(x, xb, 1048576);
    transpose_wqkv<<<dim3(48, 32), 256, 0, stream>>>(Wq, Wk, Wv, WqkvT);
  }

  // fused QKV projection + RoPE(+scale fold) epilogue: [4096,2048]x[2048,3072]
  gemm128<u16, true><<<dim3(24, 32), 256, 0, stream>>>(xb, WqkvT, QKV, 4096, 3072, 2048);

  // V slice -> V^T
  transpose_sl64<<<dim3(8, 64), 256, 0, stream>>>(QKV + 2560, 3072, Vt, 4096, 512);

  // attention v9 (QK-ahead subtile pipeline) -> Yb
  attn64<<<dim3(8, 64), 256, 0, stream>>>(QKV, Vt, Yb);

  if (!bigws) {
    transpose_cvt64<<<dim3(32, 32), 256, 0, stream>>>(Wo, WoT, 2048, 2048);
  }
  // output projection -> fp32 d_out
  gemm128<float, false><<<dim3(16, 32), 256, 0, stream>>>(Yb, WoT, outp, 4096, 2048, 2048);
}

// Round 13
// 305.233 us; speedup vs baseline: 1.1277x; 1.1277x over previous
//
#include <hip/hip_runtime.h>

using u16 = unsigned short;
using u32 = unsigned int;

typedef __attribute__((ext_vector_type(8))) __bf16 bf16x8;
typedef __attribute__((ext_vector_type(4))) float f32x4;
typedef __attribute__((ext_vector_type(16))) float f32x16;

#define DEVI __device__ __forceinline__

DEVI float bf2f(u16 u) {
  union { u32 i; float f; } v; v.i = ((u32)u) << 16; return v.f;
}
DEVI u16 f2bf(float f) {
  union { float f; u32 u; } v; v.f = f;
  u32 u = v.u;
  u32 r = (u + 0x7fffu + ((u >> 16) & 1u)) >> 16;
  return (u16)r;
}
// pack two f32 -> one u32 of 2x bf16 (compiler emits v_cvt_pk_bf16_f32)
DEVI u32 pkbf(float a, float b) {
  union { __bf16 h[2]; u32 u; } t;
  t.h[0] = (__bf16)a; t.h[1] = (__bf16)b;
  return t.u;
}

// async global->LDS, 16B per lane. LDS dest = wave-uniform base + lane*16.
DEVI void gload16(const u16* g, u16* l) {
  __builtin_amdgcn_global_load_lds(
      (const __attribute__((address_space(1))) void*)g,
      (__attribute__((address_space(3))) void*)l, 16, 0, 0);
}

// P-row (16 f32) -> PV A-fragment via cvt_pk + permlane32_swap (verified R3-R10)
DEVI bf16x8 packP(const float* pp) {
  u32 a01 = pkbf(pp[0], pp[1]);
  u32 a23 = pkbf(pp[2], pp[3]);
  u32 a45 = pkbf(pp[4], pp[5]);
  u32 a67 = pkbf(pp[6], pp[7]);
  asm volatile("v_permlane32_swap_b32 %0, %1" : "+v"(a01), "+v"(a45));
  asm volatile("v_permlane32_swap_b32 %0, %1" : "+v"(a23), "+v"(a67));
  union { u32 w[4]; bf16x8 v; } pf;
  pf.w[0] = a01; pf.w[1] = a23; pf.w[2] = a45; pf.w[3] = a67;
  return pf.v;
}

// tree-sum of 16 floats (depth 4)
DEVI float sum16(const float* p) {
  float a0 = p[0] + p[1],  a1 = p[2] + p[3];
  float a2 = p[4] + p[5],  a3 = p[6] + p[7];
  float a4 = p[8] + p[9],  a5 = p[10] + p[11];
  float a6 = p[12] + p[13], a7 = p[14] + p[15];
  float b0 = a0 + a1, b1 = a2 + a3, b2 = a4 + a5, b3 = a6 + a7;
  return (b0 + b1) + (b2 + b3);
}

// ------- 64x64 transpose+convert body: in[R][Cc] f32 -> out[Cc][R] bf16 -------
DEVI void tcvt64_body(const float* in, u16* out, int R, int Cc, int c0, int r0, int t,
                      u16 (*tile)[72]) {
  {
    int row = t >> 2, part = t & 3;
    const float* src = in + (size_t)(r0 + row) * Cc + c0 + part * 16;
    float4 f0 = ((const float4*)src)[0];
    float4 f1 = ((const float4*)src)[1];
    float4 f2 = ((const float4*)src)[2];
    float4 f3 = ((const float4*)src)[3];
    u16 v[16] = {f2bf(f0.x), f2bf(f0.y), f2bf(f0.z), f2bf(f0.w),
                 f2bf(f1.x), f2bf(f1.y), f2bf(f1.z), f2bf(f1.w),
                 f2bf(f2.x), f2bf(f2.y), f2bf(f2.z), f2bf(f2.w),
                 f2bf(f3.x), f2bf(f3.y), f2bf(f3.z), f2bf(f3.w)};
    *(uint4*)&tile[row][part * 16]     = ((const uint4*)v)[0];
    *(uint4*)&tile[row][part * 16 + 8] = ((const uint4*)v)[1];
  }
  __syncthreads();
  {
    int c = t & 63, rq = t >> 6;
    u16 v[16];
#pragma unroll
    for (int i = 0; i < 16; i++) v[i] = tile[rq * 16 + i][c];
    u16* dst = out + (size_t)(c0 + c) * R + r0 + rq * 16;
    ((uint4*)dst)[0] = ((const uint4*)v)[0];
    ((uint4*)dst)[1] = ((const uint4*)v)[1];
  }
}

// ---------------- cvt x: fp32 -> bf16, 8 elems/thread ----------------
__global__ __launch_bounds__(256) void cvt_bf16_f32(const float* __restrict__ in,
                                                    u16* __restrict__ out, int n8) {
  int i = blockIdx.x * 256 + threadIdx.x;
  if (i >= n8) return;
  const float4* fin = (const float4*)in;
  float4 a = fin[i * 2], b = fin[i * 2 + 1];
  u16 o[8] = {f2bf(a.x), f2bf(a.y), f2bf(a.z), f2bf(a.w),
              f2bf(b.x), f2bf(b.y), f2bf(b.z), f2bf(b.w)};
  ((uint4*)out)[i] = *(const uint4*)o;
}

__global__ __launch_bounds__(256) void transpose_cvt64(const float* __restrict__ in,
                                                       u16* __restrict__ out,
                                                       int R, int Cc) {
  __shared__ u16 tile[64][72];
  tcvt64_body(in, out, R, Cc, blockIdx.x * 64, blockIdx.y * 64, threadIdx.x, tile);
}

// ---- fused Wq/Wk/Wv transpose (fallback path) ----
__global__ __launch_bounds__(256) void transpose_wqkv(const float* __restrict__ Wq,
                                                      const float* __restrict__ Wk,
                                                      const float* __restrict__ Wv,
                                                      u16* __restrict__ out) {
  __shared__ u16 tile[64][72];
  int bx = blockIdx.x;
  const float* in;
  u16* dst;
  int Cc, c0;
  if (bx < 32)      { in = Wq; dst = out;                        Cc = 2048; c0 = bx * 64; }
  else if (bx < 40) { in = Wk; dst = out + (size_t)2048 * 2048;  Cc = 512;  c0 = (bx - 32) * 64; }
  else              { in = Wv; dst = out + (size_t)2560 * 2048;  Cc = 512;  c0 = (bx - 40) * 64; }
  tcvt64_body(in, dst, 2048, Cc, c0, blockIdx.y * 64, threadIdx.x, tile);
}

// ---- ALL preprocessing in ONE launch (grid-sliced), R10-verified ----
__global__ __launch_bounds__(256) void prep_all(const float* __restrict__ x,
                                                const float* __restrict__ Wq,
                                                const float* __restrict__ Wk,
                                                const float* __restrict__ Wv,
                                                const float* __restrict__ Wo,
                                                u16* __restrict__ xb,
                                                u16* __restrict__ WqkvT,
                                                u16* __restrict__ WoT) {
  __shared__ u16 tile[64][72];
  int id = blockIdx.x;
  if (id < 4096) {
    int i = id * 256 + threadIdx.x;
    const float4* fin = (const float4*)x;
    float4 a = fin[i * 2], b = fin[i * 2 + 1];
    u16 o[8] = {f2bf(a.x), f2bf(a.y), f2bf(a.z), f2bf(a.w),
                f2bf(b.x), f2bf(b.y), f2bf(b.z), f2bf(b.w)};
    ((uint4*)xb)[i] = *(const uint4*)o;
    return;
  }
  id -= 4096;
  if (id < 1536) {
    int bx = id % 48, by = id / 48;
    const float* in;
    u16* dst;
    int Cc, c0;
    if (bx < 32)      { in = Wq; dst = WqkvT;                        Cc = 2048; c0 = bx * 64; }
    else if (bx < 40) { in = Wk; dst = WqkvT + (size_t)2048 * 2048;  Cc = 512;  c0 = (bx - 32) * 64; }
    else              { in = Wv; dst = WqkvT + (size_t)2560 * 2048;  Cc = 512;  c0 = (bx - 40) * 64; }
    tcvt64_body(in, dst, 2048, Cc, c0, by * 64, threadIdx.x, tile);
    return;
  }
  id -= 1536;
  int bx = id & 31, by = id >> 5;
  tcvt64_body(Wo, WoT, 2048, 2048, bx * 64, by * 64, threadIdx.x, tile);
}

// ---- 64x64 vectorized bf16 transpose with input row-stride (V slice) ----
__global__ __launch_bounds__(256) void transpose_sl64(const u16* __restrict__ in, int ldin,
                                                      u16* __restrict__ out,
                                                      int R, int Cc) {
  __shared__ u16 tile[64][72];
  int c0 = blockIdx.x * 64, r0 = blockIdx.y * 64;
  int t = threadIdx.x;
  {
    int row = t >> 2, part = t & 3;
    const u16* src = in + (size_t)(r0 + row) * ldin + c0 + part * 16;
    uint4 a = ((const uint4*)src)[0];
    uint4 b = ((const uint4*)src)[1];
    *(uint4*)&tile[row][part * 16]     = a;
    *(uint4*)&tile[row][part * 16 + 8] = b;
  }
  __syncthreads();
  {
    int c = t & 63, rq = t >> 6;
    u16 v[16];
#pragma unroll
    for (int i = 0; i < 16; i++) v[i] = tile[rq * 16 + i][c];
    u16* dst = out + (size_t)(c0 + c) * R + r0 + rq * 16;
    ((uint4*)dst)[0] = ((const uint4*)v)[0];
    ((uint4*)dst)[1] = ((const uint4*)v)[1];
  }
}

// ---- GEMM: C[M,N] = A[M,K] * Bt[N,K]^T, 128x128 tile, BK=32, 2-phase dbuf ----
// R8-verified: T1 XCD swizzle (bijective) + ROPE epilogue. Frozen.
DEVI void cstore(u16* C, size_t idx, float v)   { C[idx] = f2bf(v); }
DEVI void cstore(float* C, size_t idx, float v) { C[idx] = v; }

template <typename TO, bool ROPE>
__global__ __launch_bounds__(256) void gemm128(const u16* __restrict__ A,
                                               const u16* __restrict__ Bt,
                                               TO* __restrict__ C,
                                               int M, int N, int K) {
  __shared__ u16 As[2 * 128 * 32];
  __shared__ u16 Bs[2 * 128 * 32];
  int tid = threadIdx.x, wid = tid >> 6, lane = tid & 63;
  int quad = lane >> 4, l15 = lane & 15;

  // T1 XCD swizzle: contiguous grid chunk per XCD (requires nwg % 8 == 0)
  int nwg = gridDim.x * gridDim.y;
  int bid = blockIdx.y * gridDim.x + blockIdx.x;
  int swz = (bid & 7) * (nwg >> 3) + (bid >> 3);
  int bx = swz % gridDim.x, by = swz / gridDim.x;
  int m0 = by * 128, n0 = bx * 128;
  int wm = (wid >> 1) * 64, wn = (wid & 1) * 64;

  int r0s = wid * 16 + (lane >> 2);
  int r1s = 64 + wid * 16 + (lane >> 2);
  int cblk = lane & 3;
  int cs0 = (cblk ^ ((r0s >> 1) & 3)) * 8;
  int cs1 = (cblk ^ ((r1s >> 1) & 3)) * 8;
  u16* lA0 = As + wid * 512 + lane * 8;
  u16* lA1 = As + (4 + wid) * 512 + lane * 8;
  u16* lB0 = Bs + wid * 512 + lane * 8;
  u16* lB1 = Bs + (4 + wid) * 512 + lane * 8;
  const u16* gA0 = A + (size_t)(m0 + r0s) * K + cs0;
  const u16* gA1 = A + (size_t)(m0 + r1s) * K + cs1;
  const u16* gB0 = Bt + (size_t)(n0 + r0s) * K + cs0;
  const u16* gB1 = Bt + (size_t)(n0 + r1s) * K + cs1;

  f32x4 acc[4][4];
  for (int i = 0; i < 4; i++)
    for (int j = 0; j < 4; j++) acc[i][j] = f32x4{0.f, 0.f, 0.f, 0.f};

  // prologue: stage K-step 0 into buf 0
  gload16(gA0, lA0);
  gload16(gA1, lA1);
  gload16(gB0, lB0);
  gload16(gB1, lB1);
  __builtin_amdgcn_s_waitcnt(0x0F70);  // vmcnt(0)
  __syncthreads();

  int cur = 0;
  for (int k0 = 0; k0 < K; k0 += 32) {
    int nb = cur ^ 1;
    if (k0 + 32 < K) {                 // prefetch next K-step into other buf
      gload16(gA0 + k0 + 32, lA0 + nb * 4096);
      gload16(gA1 + k0 + 32, lA1 + nb * 4096);
      gload16(gB0 + k0 + 32, lB0 + nb * 4096);
      gload16(gB1 + k0 + 32, lB1 + nb * 4096);
    }
    const u16* Ab = As + cur * 4096;
    const u16* Bb = Bs + cur * 4096;
    bf16x8 af[4], bf_[4];
    for (int mi = 0; mi < 4; mi++) {
      int row = wm + mi * 16 + l15;
      af[mi] = *(const bf16x8*)(Ab + row * 32 + ((quad ^ ((row >> 1) & 3)) * 8));
    }
    for (int ni = 0; ni < 4; ni++) {
      int row = wn + ni * 16 + l15;
      bf_[ni] = *(const bf16x8*)(Bb + row * 32 + ((quad ^ ((row >> 1) & 3)) * 8));
    }
    for (int mi = 0; mi < 4; mi++)
      for (int ni = 0; ni < 4; ni++)
        acc[mi][ni] = __builtin_amdgcn_mfma_f32_16x16x32_bf16(af[mi], bf_[ni], acc[mi][ni], 0, 0, 0);
    __builtin_amdgcn_s_waitcnt(0x0F70);  // vmcnt(0): prefetch landed
    __syncthreads();                     // one barrier per K-step
    cur = nb;
  }

  if (ROPE) {
    // rotate (d, d+32) pairs for Q (cols<2048, scale folded) and K (2048..2560)
#pragma unroll
    for (int ni = 0; ni < 2; ni++) {
      int nc = n0 + wn + ni * 16;            // block-uniform
      if (nc < 2560) {
        float scale = (nc < 2048) ? 0.18033688f : 1.0f;  // (1/8)*log2(e) for Q
        float inv = exp2f(-(float)(ni * 16 + l15) * 0.59161152f);  // theta^-(d/32)
#pragma unroll
        for (int mi = 0; mi < 4; mi++)
#pragma unroll
          for (int r = 0; r < 4; r++) {
            int t = (m0 + wm + mi * 16 + quad * 4 + r) & 2047;
            float sn, cs;
            __sincosf((float)t * inv, &sn, &cs);
            float xl = acc[mi][ni][r], xh = acc[mi][ni + 2][r];
            acc[mi][ni][r]     = (xl * cs - xh * sn) * scale;
            acc[mi][ni + 2][r] = (xh * cs + xl * sn) * scale;
          }
      }
    }
  }

  for (int mi = 0; mi < 4; mi++)
    for (int ni = 0; ni < 4; ni++)
      for (int r = 0; r < 4; r++) {
        int row = m0 + wm + mi * 16 + quad * 4 + r;
        int col = n0 + wn + ni * 16 + l15;
        cstore(C, (size_t)row * N + col, acc[mi][ni][r]);
      }
}

// ---------------- Flash attention: session-best (R10-measured, 88.8 us) ----------------
// Dual-strip merged loop (R9) + tree-zsum + setprio (R10). R12's QK-ahead reorder
// REGRESSED (VGPR 108->148, occupancy 18.5->10.3, attn 129.7 us): four live S-tiles
// destroyed residency -> the subtile stall is exp2/trans throughput + the 2-waves/SIMD
// grid cap, not QK-chain latency. Reverted to this proven body.
__global__ __launch_bounds__(256) void attn64(const u16* __restrict__ QKV,
                                              const u16* __restrict__ Vt,
                                              u16* __restrict__ Y) {
  __shared__ u16 Ks[2 * 64 * 64];   // 2 bufs, [key][d], granule-swizzled
  __shared__ u16 Vst[2 * 64 * 64];  // 2 bufs, [d][key], granule-swizzled

  int tid = threadIdx.x, wid = tid >> 6, lane = tid & 63;
  int l31 = lane & 31, hi = lane >> 5;
  int bh = blockIdx.y, b = bh >> 5, h = bh & 31, kvh = h >> 2;
  int p = blockIdx.x;                       // 0..7
  int jA = p, jB = 15 - p;

  // K staging (global_load_lds, linear dest + inverse-swizzled src)
  int kr  = wid * 8 + (lane >> 3);
  int kgn = lane & 7;
  const u16* gK0 = QKV + (size_t)(b * 2048 + kr) * 3072 + 2048 + kvh * 64
                 + ((kgn ^ (kr & 7)) * 8);
  u16* lK0 = Ks + wid * 512 + lane * 8;     // +buf*4096; +2048 for rows+32

  // V staging (reg-staged, swizzled ds_write)
  int vr = tid >> 3, vg = tid & 7;
  const u16* gV0 = Vt + (size_t)(kvh * 64 + vr) * 4096 + b * 2048 + vg * 8;
  u16* lV0 = Vst + vr * 64 + ((vg ^ (vr & 7)) * 8);  // +buf*4096; +2048 for d+32

  int q0wA = jA * 128 + wid * 32, qgA = q0wA + l31;
  int q0wB = jB * 128 + wid * 32, qgB = q0wB + l31;

  // Q fragments (RoPE'd + scale-folded by the QKV gemm epilogue)
  bf16x8 qfA[4], qfB[4];
  {
    const u16* qpA = QKV + (size_t)(b * 2048 + qgA) * 3072 + h * 64 + hi * 8;
    const u16* qpB = QKV + (size_t)(b * 2048 + qgB) * 3072 + h * 64 + hi * 8;
#pragma unroll
    for (int dh = 0; dh < 4; dh++) {
      qfA[dh] = *(const bf16x8*)(qpA + dh * 16);
      qfB[dh] = *(const bf16x8*)(qpB + dh * 16);
    }
  }

  f32x16 o0A, o1A, o0B, o1B;
#pragma unroll
  for (int i = 0; i < 16; i++) { o0A[i] = 0.f; o1A[i] = 0.f; o0B[i] = 0.f; o1B[i] = 0.f; }
  float zsumA = 0.f, zsumB = 0.f;

  int nkt = 2 * (jB + 1);                   // covers both strips (jB >= jA)

  // prologue: stage tile 0 into buf 0
  {
    uint4 va = *(const uint4*)(gV0);
    uint4 vb = *(const uint4*)(gV0 + 32 * 4096);
    gload16(gK0, lK0);
    gload16(gK0 + 32 * 3072, lK0 + 2048);
    __builtin_amdgcn_s_waitcnt(0x0F70);     // vmcnt(0)
    *(uint4*)(lV0)        = va;
    *(uint4*)(lV0 + 2048) = vb;
  }
  __syncthreads();

  int cur = 0;
  for (int kt = 0; kt < nkt; kt++) {
    int kbase = kt * 64;
    int nxt = cur ^ 1;
    bool more = (kt + 1 < nkt);
    uint4 va, vb;
    if (more) {                             // issue next tile's loads early
      size_t ko = (size_t)(kbase + 64);
      va = *(const uint4*)(gV0 + ko);
      vb = *(const uint4*)(gV0 + 32 * 4096 + ko);
      gload16(gK0 + ko * 3072, lK0 + nxt * 4096);
      gload16(gK0 + ko * 3072 + 32 * 3072, lK0 + nxt * 4096 + 2048);
    }

    const u16* Kb = Ks + cur * 4096;
    const u16* Vb = Vst + cur * 4096;
#pragma unroll
    for (int sub = 0; sub < 2; sub++) {
      int kb = kbase + sub * 32;
      if (kb > q0wB) break;                 // B is the longer strip
      if (kb <= q0wA) {
        // ---- dual path: shared K/V reads feed both strips ----
        f32x16 sA, sB;
#pragma unroll
        for (int i = 0; i < 16; i++) { sA[i] = 0.f; sB[i] = 0.f; }
        __builtin_amdgcn_s_setprio(1);
#pragma unroll
        for (int dh = 0; dh < 4; dh++) {
          int g = (dh * 2 + hi) ^ (l31 & 7);
          bf16x8 kf = *(const bf16x8*)(Kb + (sub * 32 + l31) * 64 + g * 8);
          sA = __builtin_amdgcn_mfma_f32_32x32x16_bf16(kf, qfA[dh], sA, 0, 0, 0);
          sB = __builtin_amdgcn_mfma_f32_32x32x16_bf16(kf, qfB[dh], sB, 0, 0, 0);
        }
        __builtin_amdgcn_s_setprio(0);
        float pbA[16], pbB[16];
        if (kb < q0wA) {                    // A full subtile
#pragma unroll
          for (int r = 0; r < 16; r++) pbA[r] = exp2f(sA[r]);
        } else {                            // A diagonal (kb == q0wA)
#pragma unroll
          for (int r = 0; r < 16; r++) {
            int key = kb + (r & 3) + 8 * (r >> 2) + 4 * hi;
            pbA[r] = (key <= qgA) ? exp2f(sA[r]) : 0.f;
          }
        }
#pragma unroll
        for (int r = 0; r < 16; r++) pbB[r] = exp2f(sB[r]);
        zsumA += sum16(pbA);
        zsumB += sum16(pbB);
        bf16x8 pfA0 = packP(pbA), pfA1 = packP(pbA + 8);
        bf16x8 pfB0 = packP(pbB), pfB1 = packP(pbB + 8);
        __builtin_amdgcn_s_setprio(1);
#pragma unroll
        for (int kk = 0; kk < 2; kk++) {
          int kgr = sub * 4 + kk * 2 + hi;
          const u16* vp = Vb + l31 * 64 + ((kgr ^ (l31 & 7)) * 8);
          bf16x8 v0 = *(const bf16x8*)(vp);
          bf16x8 v1 = *(const bf16x8*)(vp + 2048);
          bf16x8 pA = kk ? pfA1 : pfA0;
          bf16x8 pB = kk ? pfB1 : pfB0;
          o0A = __builtin_amdgcn_mfma_f32_32x32x16_bf16(pA, v0, o0A, 0, 0, 0);
          o1A = __builtin_amdgcn_mfma_f32_32x32x16_bf16(pA, v1, o1A, 0, 0, 0);
          o0B = __builtin_amdgcn_mfma_f32_32x32x16_bf16(pB, v0, o0B, 0, 0, 0);
          o1B = __builtin_amdgcn_mfma_f32_32x32x16_bf16(pB, v1, o1B, 0, 0, 0);
        }
        __builtin_amdgcn_s_setprio(0);
      } else {
        // ---- B-only path ----
        f32x16 s;
#pragma unroll
        for (int i = 0; i < 16; i++) s[i] = 0.f;
        __builtin_amdgcn_s_setprio(1);
#pragma unroll
        for (int dh = 0; dh < 4; dh++) {
          int g = (dh * 2 + hi) ^ (l31 & 7);
          bf16x8 kf = *(const bf16x8*)(Kb + (sub * 32 + l31) * 64 + g * 8);
          s = __builtin_amdgcn_mfma_f32_32x32x16_bf16(kf, qfB[dh], s, 0, 0, 0);
        }
        __builtin_amdgcn_s_setprio(0);
        float pb[16];
        if (kb < q0wB) {
#pragma unroll
          for (int r = 0; r < 16; r++) pb[r] = exp2f(s[r]);
        } else {                            // B diagonal (kb == q0wB)
#pragma unroll
          for (int r = 0; r < 16; r++) {
            int key = kb + (r & 3) + 8 * (r >> 2) + 4 * hi;
            pb[r] = (key <= qgB) ? exp2f(s[r]) : 0.f;
          }
        }
        zsumB += sum16(pb);
        bf16x8 pf0 = packP(pb), pf1 = packP(pb + 8);
        __builtin_amdgcn_s_setprio(1);
#pragma unroll
        for (int kk = 0; kk < 2; kk++) {
          int kgr = sub * 4 + kk * 2 + hi;
          const u16* vp = Vb + l31 * 64 + ((kgr ^ (l31 & 7)) * 8);
          bf16x8 v0 = *(const bf16x8*)(vp);
          bf16x8 v1 = *(const bf16x8*)(vp + 2048);
          bf16x8 pB = kk ? pf1 : pf0;
          o0B = __builtin_amdgcn_mfma_f32_32x32x16_bf16(pB, v0, o0B, 0, 0, 0);
          o1B = __builtin_amdgcn_mfma_f32_32x32x16_bf16(pB, v1, o1B, 0, 0, 0);
        }
        __builtin_amdgcn_s_setprio(0);
      }
    }

    if (more) {
      __builtin_amdgcn_s_waitcnt(0x0F70);   // vmcnt(0): K in LDS, V in regs
      *(uint4*)(lV0 + nxt * 4096)        = va;
      *(uint4*)(lV0 + nxt * 4096 + 2048) = vb;
    }
    __syncthreads();                        // one barrier per shared 64-key tile
    cur = nxt;
  }

  // epilogue, strip A
  {
    float zf = zsumA + __shfl_xor(zsumA, 32);
#pragma unroll
    for (int r = 0; r < 16; r++) {
      int qr = (r & 3) + 8 * (r >> 2) + 4 * hi;
      float zr = __shfl(zf, qr, 64);
      float inv = 1.f / zr;
      size_t row = (size_t)(b * 2048 + q0wA + qr);
      Y[row * 2048 + h * 64 + l31]      = f2bf(o0A[r] * inv);
      Y[row * 2048 + h * 64 + 32 + l31] = f2bf(o1A[r] * inv);
    }
  }
  // epilogue, strip B
  {
    float zf = zsumB + __shfl_xor(zsumB, 32);
#pragma unroll
    for (int r = 0; r < 16; r++) {
      int qr = (r & 3) + 8 * (r >> 2) + 4 * hi;
      float zr = __shfl(zf, qr, 64);
      float inv = 1.f / zr;
      size_t row = (size_t)(b * 2048 + q0wB + qr);
      Y[row * 2048 + h * 64 + l31]      = f2bf(o0B[r] * inv);
      Y[row * 2048 + h * 64 + 32 + l31] = f2bf(o1B[r] * inv);
    }
  }
}

extern "C" void kernel_launch(void* const* d_in, const int* in_sizes, int n_in,
                              void* d_out, int out_size, void* d_ws, size_t ws_size,
                              hipStream_t stream) {
  const float* x  = (const float*)d_in[0];  // [4096][2048] fp32
  const float* Wq = (const float*)d_in[1];  // [2048][2048]
  const float* Wk = (const float*)d_in[2];  // [2048][512]
  const float* Wv = (const float*)d_in[3];  // [2048][512]
  const float* Wo = (const float*)d_in[4];  // [2048][2048]
  float* outp = (float*)d_out;              // fp32 out

  // workspace (u16 units)
  u16* xb    = (u16*)d_ws;             // [4096][2048]   8388608
  u16* WqkvT = xb + 8388608;           // [3072][2048]   6291456
  u16* QKV   = WqkvT + 6291456;        // [4096][3072]  12582912
  u16* Vt    = QKV + 12582912;         // [512][4096]    2097152
  u16* Yb    = xb;                     // reuse (xb dead after QKV gemm)

  // big-ws path: WoT gets its own slab -> all preprocessing in one launch
  bool bigws = ws_size >= (size_t)(33554432) * 2;  // 64 MB
  u16* WoT = bigws ? (Vt + 2097152) : WqkvT;       // fallback: alias WqkvT

  if (bigws) {
    prep_all<<<6656, 256, 0, stream>>>(x, Wq, Wk, Wv, Wo, xb, WqkvT, WoT);
  } else {
    cvt_bf16_f32<<<4096, 256, 0, stream>>>(x, xb, 1048576);
    transpose_wqkv<<<dim3(48, 32), 256, 0, stream>>>(Wq, Wk, Wv, WqkvT);
  }

  // fused QKV projection + RoPE(+scale fold) epilogue: [4096,2048]x[2048,3072]
  gemm128<u16, true><<<dim3(24, 32), 256, 0, stream>>>(xb, WqkvT, QKV, 4096, 3072, 2048);

  // V slice -> V^T
  transpose_sl64<<<dim3(8, 64), 256, 0, stream>>>(QKV + 2560, 3072, Vt, 4096, 512);

  // attention (dual-strip + tree-zsum + setprio; R10-measured best) -> Yb
  attn64<<<dim3(8, 64), 256, 0, stream>>>(QKV, Vt, Yb);

  if (!bigws) {
    transpose_cvt64<<<dim3(32, 32), 256, 0, stream>>>(Wo, WoT, 2048, 2048);
  }
  // output projection -> fp32 d_out
  gemm128<float, false><<<dim3(16, 32), 256, 0, stream>>>(Yb, WoT, outp, 4096, 2048, 2048);
}